// Round 2
// baseline (2249.990 us; speedup 1.0000x reference)
//
#include <hip/hip_runtime.h>
#include <cstdint>
#include <cstddef>

// Problem constants
#define Hh 2048
#define Vv 32000
#define Bb 16
#define Ss 256
#define NWG 32

typedef unsigned short ushort_t;
typedef unsigned int   uint_t;
typedef unsigned long long ull_t;

typedef __attribute__((ext_vector_type(8))) short short8;   // 8 x bf16 (4 VGPRs)
typedef __attribute__((ext_vector_type(4))) float f32x4;    // MFMA accumulator

// ---- workspace layout (bytes) ----
// Zbuf : 3 physical slots x [b16][h2048] bf16 z~ = exp(y - mhat), epoch parity
//        in the SIGN BITS (values >= 0, sign bit free). Slot = 64 KiB.
// Y255 : [b][h] f32 final-step y
#define Z_OFF    0ull
#define Z_SLOT   ((size_t)Bb * Hh * 2)          // 64 KiB per slot
#define Z_BYTES  ((size_t)3 * Z_SLOT)
#define Y_OFF    (Z_OFF + Z_BYTES)
#define Y_BYTES  ((size_t)Bb * Hh * 4)
#define WS_NEED  (Y_OFF + Y_BYTES)

// Protocol (identical to the verified round-1 kernel): the DATA is the flag.
//  - step k publishes z~^k to slot phys(k%3)=(3-k%3)%3 with all bf16 sign
//    bits = k&1 (fire-and-forget 8B agent-scope stores).
//  - step k consumer spins on its granules of slot phys((k-1)%3) until the
//    sign bits == (k-1)&1. Stale data is 3 steps old -> opposite parity;
//    2-generation staleness (6 steps, same parity) is impossible because
//    publishing step k+2 requires every WG to have consumed step k, and the
//    vmcnt(0)-draining barriers bound store visibility.
//  - lagged global max: mhat_k = mhat_{k-1} + log(max_h z~^{k-1}[c,h]),
//    derived bit-identically by every WG from the staged bf16 data (max is
//    order-independent). alpha rows sum to 1, ip<=0 => z~ <= 1.
#define LD_REL(p)     __hip_atomic_load((p), __ATOMIC_RELAXED, __HIP_MEMORY_SCOPE_AGENT)
#define ST_REL(p, v)  __hip_atomic_store((p), (v), __ATOMIC_RELAXED, __HIP_MEMORY_SCOPE_AGENT)

#define SGN64 0x8000800080008000ull
#define MAG64 0x7FFF7FFF7FFF7FFFull

// LDS z tile: 16 cols x (2048 + 8 pad) bf16; col stride 2056 elem = 4112 B.
// stride%128B = 16B -> n*1028dw%32 = 4n: B-frag reads land uniform 8dw/bank.
#define ZSTR 2056

__device__ __forceinline__ float b2f_u(uint_t u) {
  union { uint_t u; float f; } x; x.u = u; return x.f;
}
__device__ __forceinline__ ushort_t f2b(float f) {
  union { float f; uint_t u; } x; x.f = f;
  uint_t u = x.u;
  return (ushort_t)((u + 0x7FFFu + ((u >> 16) & 1u)) >> 16);   // RNE f32->bf16
}
__device__ __forceinline__ uint_t umaxu(uint_t a, uint_t b) { return a > b ? a : b; }
// packed 2 x u16 max (positive bf16 ordering == integer ordering)
__device__ __forceinline__ uint_t pkmax16(uint_t a, uint_t b) {
  uint_t lo = umaxu(a & 0xFFFFu, b & 0xFFFFu);
  uint_t hi = umaxu(a >> 16, b >> 16);
  return lo | (hi << 16);
}

// ---------------------------------------------------------------------------
// Persistent scan kernel. 32 WGs x 256 threads; ALL 16 batch columns in one
// group (N=16 MFMA tile fully used). WG wl owns rows [wl*64, wl*64+64).
// K-SPLIT across the 4 waves: wave wv owns K-chunk [wv*512, wv*512+512) of
// all 4 row-tiles; partial f32 accumulators are summed through LDS.
// A-fragments (64 rows x 512 K) are register-resident bf16: 64 x short8.
// ---------------------------------------------------------------------------
__global__ __launch_bounds__(256, 1) void hmm_persist(
    const float* __restrict__ alpha,
    const float* __restrict__ beta,
    const int*  __restrict__ ids,
    ushort_t* __restrict__ Zbuf,
    float* __restrict__ Y255,
    float* __restrict__ out)
{
  const int wl   = blockIdx.x;     // 0..31 row chunk
  const int tid  = threadIdx.x;
  const int wv   = tid >> 6;       // wave 0..3 = K-chunk
  const int lane = tid & 63;
  const int lrow = lane & 15;      // MFMA col (batch col) / A row-in-tile
  const int quad = lane >> 4;

  __shared__ __align__(16) ushort_t zTf[16 * ZSTR];  // 65,792 B
  __shared__ float ipld[64 * 17];                    // [row][col], pad 17
  __shared__ __align__(16) float red[4][4][256];     // [tile][wave][lane*4]
  __shared__ uint_t mbuf[4][8];                      // per-wave packed col max

  ull_t* Zb64 = (ull_t*)Zbuf;

  // ---- preload alpha A-fragments: rows wl*64+t*16+lrow, K wv*512+kt*32 ----
  short8 afr[64];                  // [t*16 + kt]
  #pragma unroll
  for (int t = 0; t < 4; ++t) {
    #pragma unroll
    for (int kt = 0; kt < 16; ++kt) {
      const float* arow = alpha + (size_t)(wl * 64 + t * 16 + lrow) * Hh
                          + wv * 512 + kt * 32 + quad * 8;
      float4 f0 = *(const float4*)arow;
      float4 f1 = *(const float4*)(arow + 4);
      short8 fr;
      fr[0] = (short)f2b(f0.x); fr[1] = (short)f2b(f0.y);
      fr[2] = (short)f2b(f0.z); fr[3] = (short)f2b(f0.w);
      fr[4] = (short)f2b(f1.x); fr[5] = (short)f2b(f1.y);
      fr[6] = (short)f2b(f1.z); fr[7] = (short)f2b(f1.w);
      afr[t * 16 + kt] = fr;
    }
  }

  const int cg = tid & 15;         // ip-gather col
  const int r4 = tid >> 4;         // ip-gather row block (4 rows)
  float ipreg[4];

  // ---- init (k=0): y^0 = beta[:, ids[:,S-1]]; publish z~^0=exp(y^0) ----
  {
    const int ci = tid >> 4, gi = tid & 15;    // publish: col ci, granule gi
    const int h0 = (wl * 16 + gi) * 4;
    const int v  = ids[ci * Ss + (Ss - 1)];
    float y0 = beta[(size_t)(h0 + 0) * Vv + v];
    float y1 = beta[(size_t)(h0 + 1) * Vv + v];
    float y2 = beta[(size_t)(h0 + 2) * Vv + v];
    float y3 = beta[(size_t)(h0 + 3) * Vv + v];
    out[(size_t)(h0 + 0) * Bb + ci] = y0;
    out[(size_t)(h0 + 1) * Bb + ci] = y1;
    out[(size_t)(h0 + 2) * Bb + ci] = y2;
    out[(size_t)(h0 + 3) * Bb + ci] = y3;
    uint_t o0 = (uint_t)f2b(__expf(y0)) | ((uint_t)f2b(__expf(y1)) << 16);
    uint_t o1 = (uint_t)f2b(__expf(y2)) | ((uint_t)f2b(__expf(y3)) << 16);
    ST_REL(Zb64 + (size_t)ci * 512 + (wl * 16 + gi),      // slot 0, parity 0
           (ull_t)o0 | ((ull_t)o1 << 32));
    // prefetch ip_rev[1]
    const int v1 = ids[cg * Ss + (Ss - 2)];
    #pragma unroll
    for (int i = 0; i < 4; ++i)
      ipreg[i] = beta[(size_t)(wl * 64 + r4 * 4 + i) * Vv + v1];
  }

  float mprev = 0.f;               // mhat_{k-1} (same for all; used per-col
                                   // via identical lmax -> identical scalar)

  for (int k = 1; k < Ss; ++k) {
    const int   physR = (3 - ((k - 1) % 3)) % 3;
    const ull_t expS  = ((k - 1) & 1) ? SGN64 : 0ull;

    // ---- poll-is-the-load: unit j = col j, 16B at h4=2*tid (2 granules) --
    ull_t za[16], zb[16];
    {
      ull_t* base = Zb64 + (size_t)physR * 8192 + 2 * (size_t)tid;
      #pragma unroll
      for (int j = 0; j < 16; ++j) {
        za[j] = LD_REL(base + j * 512);
        zb[j] = LD_REL(base + j * 512 + 1);
      }
      while (true) {
        bool ok = true;
        #pragma unroll
        for (int j = 0; j < 16; ++j) {
          if ((za[j] & SGN64) != expS) ok = false;
          if ((zb[j] & SGN64) != expS) ok = false;
        }
        if (ok) break;
        #pragma unroll
        for (int j = 0; j < 16; ++j) {
          if ((za[j] & SGN64) != expS) za[j] = LD_REL(base + j * 512);
          if ((zb[j] & SGN64) != expS) zb[j] = LD_REL(base + j * 512 + 1);
        }
      }
    }

    // ---- stage to LDS (strip signs) + per-thread per-col max ----
    uint_t pk[8];
    {
      uint_t cm[16];
      #pragma unroll
      for (int j = 0; j < 16; ++j) {
        const ull_t a = za[j] & MAG64, b = zb[j] & MAG64;
        uint4 w4;
        w4.x = (uint_t)a; w4.y = (uint_t)(a >> 32);
        w4.z = (uint_t)b; w4.w = (uint_t)(b >> 32);
        *(uint4*)(zTf + j * ZSTR + tid * 8) = w4;
        uint_t m = pkmax16(pkmax16(w4.x, w4.y), pkmax16(w4.z, w4.w));
        cm[j] = umaxu(m & 0xFFFFu, m >> 16);
      }
      #pragma unroll
      for (int i = 0; i < 8; ++i) pk[i] = cm[2 * i] | (cm[2 * i + 1] << 16);
      #pragma unroll
      for (int d = 1; d < 64; d <<= 1) {
        #pragma unroll
        for (int i = 0; i < 8; ++i)
          pk[i] = pkmax16(pk[i], (uint_t)__shfl_xor((int)pk[i], d));
      }
      if (lane == 0) {
        #pragma unroll
        for (int i = 0; i < 8; ++i) mbuf[wv][i] = pk[i];
      }
      #pragma unroll
      for (int i = 0; i < 4; ++i)
        ipld[(r4 * 4 + i) * 17 + cg] = ipreg[i];
    }
    __syncthreads();                                   // B1

    // ---- hoisted epilogue inputs (pre-B2 so no 3rd barrier needed) ----
    float ipv[4];
    #pragma unroll
    for (int i = 0; i < 4; ++i)
      ipv[i] = ipld[(wv * 16 + quad * 4 + i) * 17 + lrow];
    uint_t mm;
    {
      uint_t v0 = mbuf[0][lrow >> 1], v1 = mbuf[1][lrow >> 1];
      uint_t v2 = mbuf[2][lrow >> 1], v3 = mbuf[3][lrow >> 1];
      uint_t mpk = pkmax16(pkmax16(v0, v1), pkmax16(v2, v3));
      mm = (lrow & 1) ? (mpk >> 16) : (mpk & 0xFFFFu);
    }
    const float lmax = __logf(b2f_u(mm << 16));  // identical across WGs/lanes of a col

    // ---- prefetch ip_rev[k+1] (overlaps MFMA) ----
    if (k < Ss - 1) {
      const int v = ids[cg * Ss + (Ss - 2 - k)];
      #pragma unroll
      for (int i = 0; i < 4; ++i)
        ipreg[i] = beta[(size_t)(wl * 64 + r4 * 4 + i) * Vv + v];
    }

    // ---- MFMA: 4 row-tile partials over this wave's K-chunk ----
    f32x4 acc[4];
    {
      f32x4 z4 = {0.f, 0.f, 0.f, 0.f};
      acc[0] = z4; acc[1] = z4; acc[2] = z4; acc[3] = z4;
    }
    const ushort_t* zb_l = zTf + lrow * ZSTR + wv * 512 + quad * 8;
    #pragma unroll
    for (int kt = 0; kt < 16; ++kt) {
      short8 bfr = *(const short8*)(zb_l + kt * 32);
      #pragma unroll
      for (int t = 0; t < 4; ++t)
        acc[t] = __builtin_amdgcn_mfma_f32_16x16x32_bf16(afr[t * 16 + kt], bfr, acc[t], 0, 0, 0);
    }

    // ---- cross-wave K-reduction through LDS ----
    #pragma unroll
    for (int t = 0; t < 4; ++t)
      if (t != wv) *(f32x4*)&red[t][wv][lane * 4] = acc[t];
    __syncthreads();                                   // B2
    f32x4 sf = acc[0];                                 // static select (no dyn idx)
    if (wv == 1) sf = acc[1];
    else if (wv == 2) sf = acc[2];
    else if (wv == 3) sf = acc[3];
    #pragma unroll
    for (int v = 0; v < 4; ++v)
      if (v != wv) sf += *(const f32x4*)&red[wv][v][lane * 4];

    // ---- epilogue: y = log(sum) + mhat_{k-1} + ip; publish z~^k ----
    const float mnew = mprev + lmax;                   // mhat_k
    float yv[4];
    #pragma unroll
    for (int i = 0; i < 4; ++i)
      yv[i] = __logf(sf[i]) + mprev + ipv[i];
    uint_t o0 = (uint_t)f2b(__expf(yv[0] - mnew)) |
                ((uint_t)f2b(__expf(yv[1] - mnew)) << 16);
    uint_t o1 = (uint_t)f2b(__expf(yv[2] - mnew)) |
                ((uint_t)f2b(__expf(yv[3] - mnew)) << 16);
    const int   physW = (3 - (k % 3)) % 3;
    const ull_t orS   = (k & 1) ? SGN64 : 0ull;
    ST_REL(Zb64 + (size_t)physW * 8192 + (size_t)lrow * 512 + (wl * 16 + wv * 4 + quad),
           ((ull_t)o0 | ((ull_t)o1 << 32)) | orS);
    // ys[k] — full 64B lines per 16 lanes now (single-writer, no amplification)
    #pragma unroll
    for (int i = 0; i < 4; ++i)
      out[(size_t)k * (Hh * Bb) + (size_t)(wl * 64 + wv * 16 + quad * 4 + i) * Bb + lrow] = yv[i];
    if (k == Ss - 1) {
      float4 yo; yo.x = yv[0]; yo.y = yv[1]; yo.z = yv[2]; yo.w = yv[3];
      *(float4*)(Y255 + (size_t)lrow * Hh + (wl * 64 + wv * 16 + quad * 4)) = yo;
    }
    mprev = mnew;
    // no 3rd barrier: zTf/ipld/mbuf writes of step k+1 are post-B2(k);
    // all their step-k readers completed before B2(k)/B1(k+1).
  }
}

// ---------------------------------------------------------------------------
// final[b] = log(sum_h e^{(g[h]-gm)+(y[h]-ym)}) - log(sum_h e^{g[h]-gm}) + ym
// ---------------------------------------------------------------------------
__global__ __launch_bounds__(256) void final_k(
    const float* __restrict__ gamma, const float* __restrict__ Y255,
    float* __restrict__ out)
{
  const int b = blockIdx.x;
  const int tid = threadIdx.x;
  __shared__ float sb[256];

  float ym = -3.0e38f;
  for (int h = tid; h < Hh; h += 256) ym = fmaxf(ym, Y255[(size_t)b * Hh + h]);
  sb[tid] = ym; __syncthreads();
  for (int off = 128; off; off >>= 1) {
    if (tid < off) sb[tid] = fmaxf(sb[tid], sb[tid + off]);
    __syncthreads();
  }
  ym = sb[0]; __syncthreads();

  float gm = -3.0e38f;
  for (int h = tid; h < Hh; h += 256) gm = fmaxf(gm, gamma[h]);
  sb[tid] = gm; __syncthreads();
  for (int off = 128; off; off >>= 1) {
    if (tid < off) sb[tid] = fmaxf(sb[tid], sb[tid + off]);
    __syncthreads();
  }
  gm = sb[0]; __syncthreads();

  float s1 = 0.f, s2 = 0.f;
  for (int h = tid; h < Hh; h += 256) {
    float gv = gamma[h] - gm;
    s1 += __expf(gv);
    s2 += __expf(gv + Y255[(size_t)b * Hh + h] - ym);
  }
  sb[tid] = s1; __syncthreads();
  for (int off = 128; off; off >>= 1) {
    if (tid < off) sb[tid] += sb[tid + off];
    __syncthreads();
  }
  s1 = sb[0]; __syncthreads();
  sb[tid] = s2; __syncthreads();
  for (int off = 128; off; off >>= 1) {
    if (tid < off) sb[tid] += sb[tid + off];
    __syncthreads();
  }
  s2 = sb[0];

  if (tid == 0)
    out[(size_t)Ss * Hh * Bb + b] = __logf(s2) - __logf(s1) + ym;
}

// ---------------------------------------------------------------------------
extern "C" void kernel_launch(void* const* d_in, const int* in_sizes, int n_in,
                              void* d_out, int out_size, void* d_ws, size_t ws_size,
                              hipStream_t stream) {
  (void)in_sizes; (void)n_in; (void)out_size;
  const int*   ids   = (const int*)d_in[0];
  const float* alpha = (const float*)d_in[1];
  const float* beta  = (const float*)d_in[2];
  const float* gamma = (const float*)d_in[3];
  float* out = (float*)d_out;
  char* ws = (char*)d_ws;

  if (ws_size < WS_NEED) return;   // clean fail rather than OOB

  ushort_t* Zbuf = (ushort_t*)(ws + Z_OFF);
  float*    Y255 = (float*)(ws + Y_OFF);

  // Epoch-pattern init: slots 0,1 -> sign=1 (0x80), slot 2 -> sign=0.
  // First read of each slot expects the opposite parity, so consumers block
  // until real data lands; also scrubs the previous launch's leftovers.
  hipMemsetAsync(ws + Z_OFF, 0x80, 2 * Z_SLOT, stream);
  hipMemsetAsync(ws + Z_OFF + 2 * Z_SLOT, 0x00, Z_SLOT, stream);

  {
    const float* a_alpha = alpha;
    const float* a_beta  = beta;
    const int*   a_ids   = ids;
    ushort_t* a_z = Zbuf;  float* a_y = Y255;  float* a_out = out;
    void* args[] = {(void*)&a_alpha, (void*)&a_beta, (void*)&a_ids,
                    (void*)&a_z, (void*)&a_y, (void*)&a_out};
    hipError_t e = hipLaunchCooperativeKernel((const void*)hmm_persist,
                                              dim3(NWG), dim3(256), args, 0, stream);
    if (e != hipSuccess) {
      hipLaunchKernelGGL(hmm_persist, dim3(NWG), dim3(256), 0, stream,
                         alpha, beta, ids, Zbuf, Y255, out);
    }
  }

  hipLaunchKernelGGL(final_k, dim3(Bb), dim3(256), 0, stream, gamma, Y255, out);
}